// Round 3
// baseline (323.648 us; speedup 1.0000x reference)
//
#include <hip/hip_runtime.h>
#include <hip/hip_bf16.h>
#include <math.h>

#define D    1024
#define C    16
#define N    256
#define TOK  8192   // B*S
#define DH   512    // D/2

using bf16x8 = __attribute__((ext_vector_type(8))) short;
using f32x4  = __attribute__((ext_vector_type(4))) float;

__device__ __forceinline__ float gelu_exact(float v) {
    return 0.5f * v * (1.0f + erff(v * 0.70710678118654752440f));
}
__device__ __forceinline__ float sigmoidf_(float z) {
    return 1.0f / (1.0f + expf(-z));
}
__device__ __forceinline__ short f2bf(float f) {          // RNE f32->bf16
    unsigned u = __float_as_uint(f);
    unsigned r = u + 0x7FFF + ((u >> 16) & 1);
    return (short)(r >> 16);
}
__device__ __forceinline__ float bf2f(short s) {
    return __uint_as_float(((unsigned)(unsigned short)s) << 16);
}

// ---------------------------------------------------------------------------
// prep: col_emb norms + zero routing counters
// ---------------------------------------------------------------------------
__global__ void prep_kernel(const float* __restrict__ col_emb, float* __restrict__ cnorm,
                            int* __restrict__ counts, int* __restrict__ cursor) {
    const int tid = threadIdx.x;              // 256
    const int c = tid >> 4, l = tid & 15;
    float acc = 0.f;
    for (int j = 0; j < 64; ++j) {
        float v = col_emb[c * D + l + 16 * j];
        acc += v * v;
    }
    for (int off = 8; off; off >>= 1) acc += __shfl_xor(acc, off, 16);
    if (l == 0) cnorm[c] = fmaxf(sqrtf(acc), 1e-12f);
    if (tid < C) { counts[tid] = 0; cursor[tid] = 0; }
}

// ---------------------------------------------------------------------------
// straight f32 -> bf16 convert (x)
// ---------------------------------------------------------------------------
__global__ __launch_bounds__(256) void conv_kernel(const float* __restrict__ src,
                                                   short* __restrict__ dst, int n4) {
    int i = blockIdx.x * 256 + threadIdx.x;
    const int stride = gridDim.x * 256;
    for (; i < n4; i += stride) {
        const float4 v = ((const float4*)src)[i];
        short4 o;
        o.x = f2bf(v.x); o.y = f2bf(v.y); o.z = f2bf(v.z); o.w = f2bf(v.w);
        ((short4*)dst)[i] = o;
    }
}

// ---------------------------------------------------------------------------
// transpose + convert: src f32 [R][Cc] -> dst bf16 [Cc][R]  (batched over z)
// ---------------------------------------------------------------------------
__global__ __launch_bounds__(256) void tconv_kernel(const float* __restrict__ src0,
        short* __restrict__ dst0, int R, int Cc) {
    __shared__ float tile[64][65];
    const int tid = threadIdx.x;
    const size_t bofs = (size_t)blockIdx.z * R * Cc;
    const float* src = src0 + bofs;
    short* dst = dst0 + bofs;
    const int cBase = blockIdx.x * 64;
    const int rBase = blockIdx.y * 64;
    const int rr = tid >> 4;           // 0..15
    const int cq = (tid & 15) * 4;
    #pragma unroll
    for (int h = 0; h < 4; ++h) {
        const int r = h * 16 + rr;
        const float4 v = *(const float4*)&src[(size_t)(rBase + r) * Cc + cBase + cq];
        tile[r][cq + 0] = v.x; tile[r][cq + 1] = v.y;
        tile[r][cq + 2] = v.z; tile[r][cq + 3] = v.w;
    }
    __syncthreads();
    #pragma unroll
    for (int h = 0; h < 4; ++h) {
        const int cc = h * 16 + rr;    // output row (= src col)
        short4 o;
        o.x = f2bf(tile[cq + 0][cc]);
        o.y = f2bf(tile[cq + 1][cc]);
        o.z = f2bf(tile[cq + 2][cc]);
        o.w = f2bf(tile[cq + 3][cc]);
        *(short4*)&dst[(size_t)(cBase + cc) * R + rBase + cq] = o;
    }
}

// ---------------------------------------------------------------------------
// unified bf16 MFMA tile GEMM, 64x64 tile, BK=64, 256 threads (2x2 waves)
// ---------------------------------------------------------------------------
template<int MODE>
__global__ __launch_bounds__(256) void mfma_tile(
        const short* __restrict__ Ag, const short* __restrict__ BTg,
        const float* __restrict__ bias, const float* __restrict__ x,
        const int* __restrict__ counts, const int* __restrict__ offs,
        const int* __restrict__ order, const float* __restrict__ wgt,
        short* __restrict__ outb, float* __restrict__ outf) {
    constexpr int KDIM = (MODE == 2) ? N : D;
    constexpr int KSTEPS = KDIM / 64;
    __shared__ short As[64 * 64];
    __shared__ short Bs[64 * 64];
    __shared__ int   tokl[64];
    __shared__ float wgl[64];

    const int tid = threadIdx.x;
    const int lane = tid & 63;
    const int wave = tid >> 6;
    const int wr = wave >> 1, wc = wave & 1;

    int cnt = 64, start = 0, col = 0, slotBase = 0, nt = 64;
    if (MODE >= 1) {
        col = blockIdx.z;
        cnt = counts[col];
        start = blockIdx.x * 64;
        if (start >= cnt) return;
        slotBase = offs[col] + start;
        nt = min(64, cnt - start);
        if (tid < 64) {
            const int i = tid < nt ? tid : nt - 1;
            const int t = order[offs[col] + start + i];
            tokl[tid] = t;
            if (MODE == 1) wgl[tid] = wgt[t];
        }
        __syncthreads();
    }

    const int rA0 = tid >> 3;                // 0..31
    const int rA1 = rA0 + 32;                // 32..63
    const int bo  = (tid & 7) * 16;          // byte offset in 128B chunk
    const char* gA0; const char* gA1;
    if (MODE == 0) {
        const size_t m0 = (size_t)blockIdx.x * 64;
        gA0 = (const char*)Ag + (m0 + rA0) * (D * 2) + bo;
        gA1 = (const char*)Ag + (m0 + rA1) * (D * 2) + bo;
    } else if (MODE == 1) {
        gA0 = (const char*)Ag + (size_t)tokl[rA0] * (D * 2) + bo;
        gA1 = (const char*)Ag + (size_t)tokl[rA1] * (D * 2) + bo;
    } else {
        const int lastSlot = offs[col] + cnt - 1;
        const int s0 = min(slotBase + rA0, lastSlot);
        const int s1 = min(slotBase + rA1, lastSlot);
        gA0 = (const char*)Ag + (size_t)s0 * (N * 2) + bo;
        gA1 = (const char*)Ag + (size_t)s1 * (N * 2) + bo;
    }
    const size_t bRowB = KDIM * 2;
    const char* gB0; const char* gB1;
    {
        size_t bbase;
        if (MODE == 0)      bbase = (size_t)blockIdx.y * 64 * bRowB;
        else if (MODE == 1) bbase = ((size_t)col * N + blockIdx.y * 64) * bRowB;
        else                bbase = ((size_t)col * D + blockIdx.y * 64) * bRowB;
        gB0 = (const char*)BTg + bbase + (size_t)rA0 * bRowB + bo;
        gB1 = (const char*)BTg + bbase + (size_t)rA1 * bRowB + bo;
    }
    char* const wA0 = (char*)As + rA0 * 128 + (bo ^ ((rA0 & 7) << 4));
    char* const wA1 = (char*)As + rA1 * 128 + (bo ^ ((rA1 & 7) << 4));
    char* const wB0 = (char*)Bs + rA0 * 128 + (bo ^ ((rA0 & 7) << 4));
    char* const wB1 = (char*)Bs + rA1 * 128 + (bo ^ ((rA1 & 7) << 4));

    const int mrow = wr * 32 + (lane & 15);
    const int nrow = wc * 32 + (lane & 15);
    const int kbB  = (lane >> 4) * 16;
    const int swm  = (mrow & 7) << 4;
    const int swn  = (nrow & 7) << 4;

    f32x4 acc[2][2] = {};
    for (int kk = 0; kk < KSTEPS; ++kk) {
        *(bf16x8*)wA0 = *(const bf16x8*)gA0;
        *(bf16x8*)wA1 = *(const bf16x8*)gA1;
        *(bf16x8*)wB0 = *(const bf16x8*)gB0;
        *(bf16x8*)wB1 = *(const bf16x8*)gB1;
        gA0 += 128; gA1 += 128; gB0 += 128; gB1 += 128;
        __syncthreads();
        #pragma unroll
        for (int ks = 0; ks < 2; ++ks) {
            bf16x8 aF[2], bF[2];
            #pragma unroll
            for (int i = 0; i < 2; ++i)
                aF[i] = *(const bf16x8*)((const char*)As + (mrow + i * 16) * 128
                                         + ((kbB + ks * 64) ^ swm));
            #pragma unroll
            for (int j = 0; j < 2; ++j)
                bF[j] = *(const bf16x8*)((const char*)Bs + (nrow + j * 16) * 128
                                         + ((kbB + ks * 64) ^ swn));
            #pragma unroll
            for (int i = 0; i < 2; ++i)
                #pragma unroll
                for (int j = 0; j < 2; ++j)
                    acc[i][j] = __builtin_amdgcn_mfma_f32_16x16x32_bf16(
                                    aF[i], bF[j], acc[i][j], 0, 0, 0);
        }
        __syncthreads();
    }

    const int crow = (lane >> 4) * 4;
    const int ccol = lane & 15;
    if (MODE == 0) {
        const int m0 = blockIdx.x * 64;
        const int n0 = blockIdx.y * 64;
        #pragma unroll
        for (int i = 0; i < 2; ++i)
            #pragma unroll
            for (int j = 0; j < 2; ++j) {
                const int n = n0 + wc * 32 + j * 16 + ccol;
                const float bb = bias[n];
                #pragma unroll
                for (int r = 0; r < 4; ++r) {
                    const int m = m0 + wr * 32 + i * 16 + crow + r;
                    outb[(size_t)m * DH + n] = f2bf(gelu_exact(acc[i][j][r] + bb));
                }
            }
    } else if (MODE == 1) {
        const int n0 = blockIdx.y * 64;
        #pragma unroll
        for (int i = 0; i < 2; ++i)
            #pragma unroll
            for (int j = 0; j < 2; ++j) {
                const int n = n0 + wc * 32 + j * 16 + ccol;
                const float bb = bias[col * N + n];
                #pragma unroll
                for (int r = 0; r < 4; ++r) {
                    const int il = wr * 32 + i * 16 + crow + r;
                    if (il < nt) {
                        const float v = gelu_exact(acc[i][j][r] + bb) * wgl[il];
                        outb[(size_t)(slotBase + il) * N + n] = f2bf(v);
                    }
                }
            }
    } else {
        const int n0 = blockIdx.y * 64;
        #pragma unroll
        for (int i = 0; i < 2; ++i)
            #pragma unroll
            for (int j = 0; j < 2; ++j) {
                const int dcol = n0 + wc * 32 + j * 16 + ccol;
                const float bb = bias[dcol];
                #pragma unroll
                for (int r = 0; r < 4; ++r) {
                    const int il = wr * 32 + i * 16 + crow + r;
                    if (il < nt) {
                        const size_t ofs = (size_t)tokl[il] * D + dcol;
                        outf[ofs] = acc[i][j][r] + bb + x[ofs];
                    }
                }
            }
    }
}

// ---------------------------------------------------------------------------
// route: one wave per token, no LDS, no block syncs.
// logits = sim + sigmoid(H @ gate_w2 + b2); top-1 idx + softmax weight
// ---------------------------------------------------------------------------
__global__ __launch_bounds__(256) void route_kernel(
        const float* __restrict__ x, const short* __restrict__ Hb,
        const float* __restrict__ col_emb, const float* __restrict__ cnorm,
        const float* __restrict__ w2, const float* __restrict__ b2,
        int* __restrict__ idx, float* __restrict__ wgt, int* __restrict__ counts) {
    const int tid = threadIdx.x;
    const int lane = tid & 63;
    const int wv = tid >> 6;
    const int t = blockIdx.x * 4 + wv;

    // private x slice: 16 consecutive-by-chunk floats, coalesced float4 loads
    float xr[16];
    #pragma unroll
    for (int ch = 0; ch < 4; ++ch) {
        const float4 v = *(const float4*)&x[(size_t)t * D + ch * 256 + lane * 4];
        xr[ch * 4 + 0] = v.x; xr[ch * 4 + 1] = v.y;
        xr[ch * 4 + 2] = v.z; xr[ch * 4 + 3] = v.w;
    }
    float ss = 0.f;
    #pragma unroll
    for (int i = 0; i < 16; ++i) ss += xr[i] * xr[i];
    #pragma unroll
    for (int off = 32; off; off >>= 1) ss += __shfl_xor(ss, off);
    const float xn = fmaxf(sqrtf(ss), 1e-12f);

    // similarity partials for all 16 columns (col_emb is L1/L2-resident)
    float sim[C];
    #pragma unroll
    for (int c = 0; c < C; ++c) {
        float a = 0.f;
        #pragma unroll
        for (int ch = 0; ch < 4; ++ch) {
            const float4 e = *(const float4*)&col_emb[c * D + ch * 256 + lane * 4];
            a += xr[ch * 4 + 0] * e.x + xr[ch * 4 + 1] * e.y
               + xr[ch * 4 + 2] * e.z + xr[ch * 4 + 3] * e.w;
        }
        sim[c] = a;
    }
    #pragma unroll
    for (int off = 32; off; off >>= 1)
        #pragma unroll
        for (int c = 0; c < C; ++c) sim[c] += __shfl_xor(sim[c], off);

    // gate2 partials: lane owns 8 H-elements (rows lane*8..lane*8+7 of w2)
    float hr[8];
    {
        const bf16x8 hv = *(const bf16x8*)&Hb[(size_t)t * DH + lane * 8];
        #pragma unroll
        for (int j = 0; j < 8; ++j) hr[j] = bf2f(hv[j]);
    }
    float g[C] = {};
    #pragma unroll
    for (int j = 0; j < 8; ++j) {
        const float hj = hr[j];
        const float* wrow = &w2[(lane * 8 + j) * C];
        #pragma unroll
        for (int cq = 0; cq < 4; ++cq) {
            const float4 w4 = *(const float4*)&wrow[cq * 4];
            g[cq * 4 + 0] += hj * w4.x; g[cq * 4 + 1] += hj * w4.y;
            g[cq * 4 + 2] += hj * w4.z; g[cq * 4 + 3] += hj * w4.w;
        }
    }
    #pragma unroll
    for (int off = 32; off; off >>= 1)
        #pragma unroll
        for (int c = 0; c < C; ++c) g[c] += __shfl_xor(g[c], off);

    // logits, top-1, softmax weight (redundant on all lanes; lane 0 writes)
    float logit[C];
    #pragma unroll
    for (int c = 0; c < C; ++c)
        logit[c] = sim[c] / (xn * cnorm[c]) + sigmoidf_(g[c] + b2[c]);
    float mx = logit[0]; int am = 0;
    #pragma unroll
    for (int c = 1; c < C; ++c)
        if (logit[c] > mx) { mx = logit[c]; am = c; }
    float se = 0.f;
    #pragma unroll
    for (int c = 0; c < C; ++c) se += expf(logit[c] - mx);
    if (lane == 0) {
        idx[t] = am;
        wgt[t] = 1.f / se;
        atomicAdd(&counts[am], 1);
    }
}

__global__ void scan_kernel(const int* __restrict__ counts, int* __restrict__ offs,
                            int* __restrict__ cursor) {
    if (threadIdx.x == 0) {
        int s = 0;
        for (int c = 0; c < C; ++c) { offs[c] = s; cursor[c] = s; s += counts[c]; }
    }
}

__global__ void scatter_kernel(const int* __restrict__ idx, int* __restrict__ cursor,
                               int* __restrict__ order) {
    const int t = blockIdx.x * 256 + threadIdx.x;
    const int c = idx[t];
    const int p = atomicAdd(&cursor[c], 1);
    order[p] = t;
}

// ---------------------------------------------------------------------------
// layernorm, in-place on out
// ---------------------------------------------------------------------------
__global__ __launch_bounds__(256) void ln_kernel(float* __restrict__ out,
        const float* __restrict__ g, const float* __restrict__ b) {
    __shared__ float wr_[4], wr2[4];
    const int t = blockIdx.x, tid = threadIdx.x;
    const float4 v = *(const float4*)&out[(size_t)t * D + tid * 4];
    float s = v.x + v.y + v.z + v.w;
    float s2 = v.x * v.x + v.y * v.y + v.z * v.z + v.w * v.w;
    for (int off = 32; off; off >>= 1) { s += __shfl_xor(s, off); s2 += __shfl_xor(s2, off); }
    if ((tid & 63) == 0) { wr_[tid >> 6] = s; wr2[tid >> 6] = s2; }
    __syncthreads();
    const float sum = wr_[0] + wr_[1] + wr_[2] + wr_[3];
    const float sum2 = wr2[0] + wr2[1] + wr2[2] + wr2[3];
    const float mu = sum * (1.f / D);
    const float var = sum2 * (1.f / D) - mu * mu;
    const float inv = rsqrtf(var + 1e-5f);
    const float4 g4 = *(const float4*)&g[tid * 4];
    const float4 b4 = *(const float4*)&b[tid * 4];
    float4 o;
    o.x = (v.x - mu) * inv * g4.x + b4.x;
    o.y = (v.y - mu) * inv * g4.y + b4.y;
    o.z = (v.z - mu) * inv * g4.z + b4.z;
    o.w = (v.w - mu) * inv * g4.w + b4.w;
    *(float4*)&out[(size_t)t * D + tid * 4] = o;
}

// ---------------------------------------------------------------------------
extern "C" void kernel_launch(void* const* d_in, const int* in_sizes, int n_in,
                              void* d_out, int out_size, void* d_ws, size_t ws_size,
                              hipStream_t stream) {
    const float* x       = (const float*)d_in[0];
    const float* col_emb = (const float*)d_in[1];
    const float* gate_w1 = (const float*)d_in[2];
    const float* gate_b1 = (const float*)d_in[3];
    const float* gate_w2 = (const float*)d_in[4];
    const float* gate_b2 = (const float*)d_in[5];
    const float* W_cols  = (const float*)d_in[6];
    const float* b_cols  = (const float*)d_in[7];
    const float* proj_w  = (const float*)d_in[8];
    const float* proj_b  = (const float*)d_in[9];
    const float* ln_g    = (const float*)d_in[10];
    const float* ln_b    = (const float*)d_in[11];
    float* out = (float*)d_out;

    char* w = (char*)d_ws;
    short* xb    = (short*)w;  w += (size_t)TOK * D * 2;           // 16 MB
    short* Hb    = (short*)w;  w += (size_t)TOK * DH * 2;          //  8 MB
    short* actb  = (short*)w;  w += (size_t)TOK * N * 2 + 65536;   //  4 MB + slack
    short* w1T   = (short*)w;  w += (size_t)DH * D * 2;            //  1 MB
    short* WcT   = (short*)w;  w += (size_t)C * N * D * 2;         //  8 MB
    short* pwT   = (short*)w;  w += (size_t)C * D * N * 2;         //  8 MB
    float* wgt   = (float*)w;  w += TOK * 4;
    float* cnorm = (float*)w;  w += 64;
    int*   idx   = (int*)w;    w += TOK * 4;
    int*   order = (int*)w;    w += TOK * 4;
    int*   counts= (int*)w;    w += 64;
    int*   offs  = (int*)w;    w += 64;
    int*   cursor= (int*)w;    w += 64;

    hipLaunchKernelGGL(prep_kernel, dim3(1), dim3(256), 0, stream,
                       col_emb, cnorm, counts, cursor);
    hipLaunchKernelGGL(conv_kernel, dim3(2048), dim3(256), 0, stream,
                       x, xb, TOK * D / 4);
    hipLaunchKernelGGL(tconv_kernel, dim3(DH / 64, D / 64, 1), dim3(256), 0, stream,
                       gate_w1, w1T, D, DH);
    hipLaunchKernelGGL(tconv_kernel, dim3(N / 64, D / 64, C), dim3(256), 0, stream,
                       W_cols, WcT, D, N);
    hipLaunchKernelGGL(tconv_kernel, dim3(D / 64, N / 64, C), dim3(256), 0, stream,
                       proj_w, pwT, N, D);
    // gate GEMM (bf16 MFMA) -> Hb
    hipLaunchKernelGGL((mfma_tile<0>), dim3(TOK / 64, DH / 64, 1), dim3(256), 0, stream,
                       xb, w1T, gate_b1, nullptr, nullptr, nullptr, nullptr, nullptr,
                       Hb, nullptr);
    hipLaunchKernelGGL(route_kernel, dim3(TOK / 4), dim3(256), 0, stream,
                       x, Hb, col_emb, cnorm, gate_w2, gate_b2, idx, wgt, counts);
    hipLaunchKernelGGL(scan_kernel, dim3(1), dim3(64), 0, stream, counts, offs, cursor);
    hipLaunchKernelGGL(scatter_kernel, dim3(TOK / 256), dim3(256), 0, stream,
                       idx, cursor, order);
    // column GEMM1 (grouped, bf16 MFMA) -> actb
    hipLaunchKernelGGL((mfma_tile<1>), dim3(TOK / 64, N / 64, C), dim3(256), 0, stream,
                       xb, WcT, b_cols, nullptr, counts, offs, order, wgt,
                       actb, nullptr);
    // column GEMM2 (grouped, bf16 MFMA) -> out (+bias+residual)
    hipLaunchKernelGGL((mfma_tile<2>), dim3(TOK / 64, D / 64, C), dim3(256), 0, stream,
                       actb, pwT, proj_b, x, counts, offs, order, wgt,
                       nullptr, out);
    hipLaunchKernelGGL(ln_kernel, dim3(TOK), dim3(256), 0, stream, out, ln_g, ln_b);
}

// Round 4
// 207.161 us; speedup vs baseline: 1.5623x; 1.5623x over previous
//
#include <hip/hip_runtime.h>
#include <hip/hip_bf16.h>
#include <math.h>

#define D    1024
#define C    16
#define N    256
#define TOK  8192   // B*S
#define DH   512    // D/2
#define RT_T 16     // route: tokens per block

using bf16x8 = __attribute__((ext_vector_type(8))) short;
using f32x4  = __attribute__((ext_vector_type(4))) float;

__device__ __forceinline__ float gelu_exact(float v) {
    return 0.5f * v * (1.0f + erff(v * 0.70710678118654752440f));
}
__device__ __forceinline__ float sigmoidf_(float z) {
    return 1.0f / (1.0f + expf(-z));
}
__device__ __forceinline__ short f2bf(float f) {          // RNE f32->bf16
    unsigned u = __float_as_uint(f);
    unsigned r = u + 0x7FFF + ((u >> 16) & 1);
    return (short)(r >> 16);
}
__device__ __forceinline__ float bf2f(short s) {
    return __uint_as_float(((unsigned)(unsigned short)s) << 16);
}

// ---------------------------------------------------------------------------
// prep: col_emb norms
// ---------------------------------------------------------------------------
__global__ void prep_kernel(const float* __restrict__ col_emb, float* __restrict__ cnorm) {
    const int tid = threadIdx.x;              // 256
    const int c = tid >> 4, l = tid & 15;
    float acc = 0.f;
    for (int j = 0; j < 64; ++j) {
        float v = col_emb[c * D + l + 16 * j];
        acc += v * v;
    }
    for (int off = 8; off; off >>= 1) acc += __shfl_xor(acc, off, 16);
    if (l == 0) cnorm[c] = fmaxf(sqrtf(acc), 1e-12f);
}

// ---------------------------------------------------------------------------
// straight f32 -> bf16 convert (x)
// ---------------------------------------------------------------------------
__global__ __launch_bounds__(256) void conv_kernel(const float* __restrict__ src,
                                                   short* __restrict__ dst, int n4) {
    int i = blockIdx.x * 256 + threadIdx.x;
    const int stride = gridDim.x * 256;
    for (; i < n4; i += stride) {
        const float4 v = ((const float4*)src)[i];
        short4 o;
        o.x = f2bf(v.x); o.y = f2bf(v.y); o.z = f2bf(v.z); o.w = f2bf(v.w);
        ((short4*)dst)[i] = o;
    }
}

// ---------------------------------------------------------------------------
// transpose + convert: src f32 [R][Cc] -> dst bf16 [Cc][R]  (batched over z)
// ---------------------------------------------------------------------------
__global__ __launch_bounds__(256) void tconv_kernel(const float* __restrict__ src0,
        short* __restrict__ dst0, int R, int Cc) {
    __shared__ float tile[64][65];
    const int tid = threadIdx.x;
    const size_t bofs = (size_t)blockIdx.z * R * Cc;
    const float* src = src0 + bofs;
    short* dst = dst0 + bofs;
    const int cBase = blockIdx.x * 64;
    const int rBase = blockIdx.y * 64;
    const int rr = tid >> 4;           // 0..15
    const int cq = (tid & 15) * 4;
    #pragma unroll
    for (int h = 0; h < 4; ++h) {
        const int r = h * 16 + rr;
        const float4 v = *(const float4*)&src[(size_t)(rBase + r) * Cc + cBase + cq];
        tile[r][cq + 0] = v.x; tile[r][cq + 1] = v.y;
        tile[r][cq + 2] = v.z; tile[r][cq + 3] = v.w;
    }
    __syncthreads();
    #pragma unroll
    for (int h = 0; h < 4; ++h) {
        const int cc = h * 16 + rr;    // output row (= src col)
        short4 o;
        o.x = f2bf(tile[cq + 0][cc]);
        o.y = f2bf(tile[cq + 1][cc]);
        o.z = f2bf(tile[cq + 2][cc]);
        o.w = f2bf(tile[cq + 3][cc]);
        *(short4*)&dst[(size_t)(cBase + cc) * R + rBase + cq] = o;
    }
}

// ---------------------------------------------------------------------------
// unified bf16 MFMA tile GEMM, 64x64 tile, BK=64, 256 threads (2x2 waves)
// ---------------------------------------------------------------------------
template<int MODE>
__global__ __launch_bounds__(256) void mfma_tile(
        const short* __restrict__ Ag, const short* __restrict__ BTg,
        const float* __restrict__ bias, const float* __restrict__ x,
        const int* __restrict__ counts, const int* __restrict__ offs,
        const int* __restrict__ order, const float* __restrict__ wgt,
        short* __restrict__ outb, float* __restrict__ outf) {
    constexpr int KDIM = (MODE == 2) ? N : D;
    constexpr int KSTEPS = KDIM / 64;
    __shared__ short As[64 * 64];
    __shared__ short Bs[64 * 64];
    __shared__ int   tokl[64];
    __shared__ float wgl[64];

    const int tid = threadIdx.x;
    const int lane = tid & 63;
    const int wave = tid >> 6;
    const int wr = wave >> 1, wc = wave & 1;

    int cnt = 64, start = 0, col = 0, slotBase = 0, nt = 64;
    if (MODE >= 1) {
        col = blockIdx.z;
        cnt = counts[col];
        start = blockIdx.x * 64;
        if (start >= cnt) return;
        slotBase = offs[col] + start;
        nt = min(64, cnt - start);
        if (tid < 64) {
            const int i = tid < nt ? tid : nt - 1;
            const int t = order[offs[col] + start + i];
            tokl[tid] = t;
            if (MODE == 1) wgl[tid] = wgt[t];
        }
        __syncthreads();
    }

    const int rA0 = tid >> 3;                // 0..31
    const int rA1 = rA0 + 32;                // 32..63
    const int bo  = (tid & 7) * 16;          // byte offset in 128B chunk
    const char* gA0; const char* gA1;
    if (MODE == 0) {
        const size_t m0 = (size_t)blockIdx.x * 64;
        gA0 = (const char*)Ag + (m0 + rA0) * (D * 2) + bo;
        gA1 = (const char*)Ag + (m0 + rA1) * (D * 2) + bo;
    } else if (MODE == 1) {
        gA0 = (const char*)Ag + (size_t)tokl[rA0] * (D * 2) + bo;
        gA1 = (const char*)Ag + (size_t)tokl[rA1] * (D * 2) + bo;
    } else {
        const int lastSlot = offs[col] + cnt - 1;
        const int s0 = min(slotBase + rA0, lastSlot);
        const int s1 = min(slotBase + rA1, lastSlot);
        gA0 = (const char*)Ag + (size_t)s0 * (N * 2) + bo;
        gA1 = (const char*)Ag + (size_t)s1 * (N * 2) + bo;
    }
    const size_t bRowB = KDIM * 2;
    const char* gB0; const char* gB1;
    {
        size_t bbase;
        if (MODE == 0)      bbase = (size_t)blockIdx.y * 64 * bRowB;
        else if (MODE == 1) bbase = ((size_t)col * N + blockIdx.y * 64) * bRowB;
        else                bbase = ((size_t)col * D + blockIdx.y * 64) * bRowB;
        gB0 = (const char*)BTg + bbase + (size_t)rA0 * bRowB + bo;
        gB1 = (const char*)BTg + bbase + (size_t)rA1 * bRowB + bo;
    }
    char* const wA0 = (char*)As + rA0 * 128 + (bo ^ ((rA0 & 7) << 4));
    char* const wA1 = (char*)As + rA1 * 128 + (bo ^ ((rA1 & 7) << 4));
    char* const wB0 = (char*)Bs + rA0 * 128 + (bo ^ ((rA0 & 7) << 4));
    char* const wB1 = (char*)Bs + rA1 * 128 + (bo ^ ((rA1 & 7) << 4));

    const int mrow = wr * 32 + (lane & 15);
    const int nrow = wc * 32 + (lane & 15);
    const int kbB  = (lane >> 4) * 16;
    const int swm  = (mrow & 7) << 4;
    const int swn  = (nrow & 7) << 4;

    f32x4 acc[2][2] = {};
    for (int kk = 0; kk < KSTEPS; ++kk) {
        *(bf16x8*)wA0 = *(const bf16x8*)gA0;
        *(bf16x8*)wA1 = *(const bf16x8*)gA1;
        *(bf16x8*)wB0 = *(const bf16x8*)gB0;
        *(bf16x8*)wB1 = *(const bf16x8*)gB1;
        gA0 += 128; gA1 += 128; gB0 += 128; gB1 += 128;
        __syncthreads();
        #pragma unroll
        for (int ks = 0; ks < 2; ++ks) {
            bf16x8 aF[2], bF[2];
            #pragma unroll
            for (int i = 0; i < 2; ++i)
                aF[i] = *(const bf16x8*)((const char*)As + (mrow + i * 16) * 128
                                         + ((kbB + ks * 64) ^ swm));
            #pragma unroll
            for (int j = 0; j < 2; ++j)
                bF[j] = *(const bf16x8*)((const char*)Bs + (nrow + j * 16) * 128
                                         + ((kbB + ks * 64) ^ swn));
            #pragma unroll
            for (int i = 0; i < 2; ++i)
                #pragma unroll
                for (int j = 0; j < 2; ++j)
                    acc[i][j] = __builtin_amdgcn_mfma_f32_16x16x32_bf16(
                                    aF[i], bF[j], acc[i][j], 0, 0, 0);
        }
        __syncthreads();
    }

    const int crow = (lane >> 4) * 4;
    const int ccol = lane & 15;
    if (MODE == 0) {
        const int m0 = blockIdx.x * 64;
        const int n0 = blockIdx.y * 64;
        #pragma unroll
        for (int i = 0; i < 2; ++i)
            #pragma unroll
            for (int j = 0; j < 2; ++j) {
                const int n = n0 + wc * 32 + j * 16 + ccol;
                const float bb = bias[n];
                #pragma unroll
                for (int r = 0; r < 4; ++r) {
                    const int m = m0 + wr * 32 + i * 16 + crow + r;
                    outb[(size_t)m * DH + n] = f2bf(gelu_exact(acc[i][j][r] + bb));
                }
            }
    } else if (MODE == 1) {
        const int n0 = blockIdx.y * 64;
        #pragma unroll
        for (int i = 0; i < 2; ++i)
            #pragma unroll
            for (int j = 0; j < 2; ++j) {
                const int n = n0 + wc * 32 + j * 16 + ccol;
                const float bb = bias[col * N + n];
                #pragma unroll
                for (int r = 0; r < 4; ++r) {
                    const int il = wr * 32 + i * 16 + crow + r;
                    if (il < nt) {
                        const float v = gelu_exact(acc[i][j][r] + bb) * wgl[il];
                        outb[(size_t)(slotBase + il) * N + n] = f2bf(v);
                    }
                }
            }
    } else {
        const int n0 = blockIdx.y * 64;
        #pragma unroll
        for (int i = 0; i < 2; ++i)
            #pragma unroll
            for (int j = 0; j < 2; ++j) {
                const int dcol = n0 + wc * 32 + j * 16 + ccol;
                const float bb = bias[dcol];
                #pragma unroll
                for (int r = 0; r < 4; ++r) {
                    const int il = wr * 32 + i * 16 + crow + r;
                    if (il < nt) {
                        const size_t ofs = (size_t)tokl[il] * D + dcol;
                        outf[ofs] = acc[i][j][r] + bb + x[ofs];
                    }
                }
            }
    }
}

// ---------------------------------------------------------------------------
// route v3: weights-in-registers, activations streamed coalesced.
// Block: 256 threads, RT_T tokens. Thread holds col_emb[16][d:tid*4+0..3]
// and w2[tid*2+0..1][16]. Per token: 1 float4 x-load + 1 dword H-load,
// 96 FMAs of partials, swizzled-LDS transpose-reduce. No atomics.
// ---------------------------------------------------------------------------
__global__ __launch_bounds__(256) void route_kernel(
        const float* __restrict__ x, const short* __restrict__ Hb,
        const float* __restrict__ col_emb, const float* __restrict__ cnorm,
        const float* __restrict__ w2, const float* __restrict__ b2,
        int* __restrict__ idx, float* __restrict__ wgt) {
    __shared__ float P[256][33];     // partials, stride 33 (bank-free)
    __shared__ float Q[8][33];       // second-level partials
    __shared__ float SSW[4];         // per-wave ||x||^2 partials
    __shared__ float FL[RT_T][34];   // finalized [sim16 | g16 | ss] per token
    const int tid = threadIdx.x;
    const int lane = tid & 63;
    const int t0 = blockIdx.x * RT_T;
    const int swz = (tid & 7) << 2;  // dump-side XOR swizzle (quad granularity)

    // --- persistent weight registers ---
    float4 ce[C];                    // col_emb[c][tid*4 .. +3]
    #pragma unroll
    for (int c = 0; c < C; ++c)
        ce[c] = *(const float4*)&col_emb[c * D + tid * 4];
    float w2r[2][C];                 // w2[tid*2 + r][c]
    #pragma unroll
    for (int r2 = 0; r2 < 2; ++r2)
        #pragma unroll
        for (int cq = 0; cq < 4; ++cq) {
            const float4 v = *(const float4*)&w2[(tid * 2 + r2) * C + cq * 4];
            w2r[r2][cq * 4 + 0] = v.x; w2r[r2][cq * 4 + 1] = v.y;
            w2r[r2][cq * 4 + 2] = v.z; w2r[r2][cq * 4 + 3] = v.w;
        }

    for (int ti = 0; ti < RT_T; ++ti) {
        const int t = t0 + ti;
        // --- streamed activations (fully coalesced) ---
        const float4 xv = *(const float4*)&x[(size_t)t * D + tid * 4];
        const unsigned hu = *(const unsigned*)&Hb[(size_t)t * DH + tid * 2];
        const float h0 = bf2f((short)(hu & 0xffff));
        const float h1 = bf2f((short)(hu >> 16));
        // --- partials ---
        float pv[32];
        #pragma unroll
        for (int c = 0; c < C; ++c)
            pv[c] = xv.x * ce[c].x + xv.y * ce[c].y + xv.z * ce[c].z + xv.w * ce[c].w;
        #pragma unroll
        for (int c = 0; c < C; ++c)
            pv[C + c] = h0 * w2r[0][c] + h1 * w2r[1][c];
        float ssp = xv.x * xv.x + xv.y * xv.y + xv.z * xv.z + xv.w * xv.w;
        #pragma unroll
        for (int off = 32; off; off >>= 1) ssp += __shfl_xor(ssp, off);
        if (lane == 0) SSW[tid >> 6] = ssp;
        // --- dump (swizzled: write col c^swz; both sides <=2-way banks) ---
        #pragma unroll
        for (int c = 0; c < 32; ++c)
            P[tid][c ^ swz] = pv[c];
        __syncthreads();
        // --- gather: thread (v=tid&31, j=tid>>5) sums rows j*32..j*32+31 ---
        {
            const int v = tid & 31, jj = tid >> 5;
            float s = 0.f;
            #pragma unroll
            for (int k = 0; k < 32; ++k) {
                const int row = jj * 32 + k;
                s += P[row][v ^ ((row & 7) << 2)];
            }
            Q[jj][v] = s;
        }
        __syncthreads();
        // --- final sum + park in FL ---
        if (tid < 32) {
            float f = 0.f;
            #pragma unroll
            for (int j2 = 0; j2 < 8; ++j2) f += Q[j2][tid];
            FL[ti][tid] = f;
        } else if (tid == 32) {
            FL[ti][32] = SSW[0] + SSW[1] + SSW[2] + SSW[3];
        }
        __syncthreads();
    }

    // --- finalize: one thread per token ---
    if (tid < RT_T) {
        const int t = t0 + tid;
        const float xn = fmaxf(sqrtf(FL[tid][32]), 1e-12f);
        float logit[C];
        #pragma unroll
        for (int c = 0; c < C; ++c)
            logit[c] = FL[tid][c] / (xn * cnorm[c])
                     + sigmoidf_(FL[tid][C + c] + b2[c]);
        float mx = logit[0]; int am = 0;
        #pragma unroll
        for (int c = 1; c < C; ++c)
            if (logit[c] > mx) { mx = logit[c]; am = c; }
        float se = 0.f;
        #pragma unroll
        for (int c = 0; c < C; ++c) se += expf(logit[c] - mx);
        idx[t] = am;
        wgt[t] = 1.f / se;
    }
}

// ---------------------------------------------------------------------------
// histogram: counts/offs/cursor from idx (single block, replaces atomics)
// ---------------------------------------------------------------------------
__global__ __launch_bounds__(256) void hist_kernel(const int* __restrict__ idx,
        int* __restrict__ counts, int* __restrict__ offs, int* __restrict__ cursor) {
    __shared__ int h[C];
    const int tid = threadIdx.x;
    if (tid < C) h[tid] = 0;
    __syncthreads();
    for (int t = tid; t < TOK; t += 256) atomicAdd(&h[idx[t]], 1);
    __syncthreads();
    if (tid == 0) {
        int s = 0;
        for (int c = 0; c < C; ++c) {
            counts[c] = h[c]; offs[c] = s; cursor[c] = s; s += h[c];
        }
    }
}

// ---------------------------------------------------------------------------
// scatter: block-local ranges -> 16 global atomics per block (512 total)
// ---------------------------------------------------------------------------
__global__ __launch_bounds__(256) void scatter_kernel(const int* __restrict__ idx,
        int* __restrict__ cursor, int* __restrict__ order) {
    __shared__ int lh[C];
    __shared__ int lbase[C];
    const int tid = threadIdx.x;
    const int t = blockIdx.x * 256 + tid;
    if (tid < C) lh[tid] = 0;
    __syncthreads();
    const int c = idx[t];
    const int p = atomicAdd(&lh[c], 1);
    __syncthreads();
    if (tid < C) lbase[tid] = atomicAdd(&cursor[tid], lh[tid]);
    __syncthreads();
    order[lbase[c] + p] = t;
}

// ---------------------------------------------------------------------------
// layernorm, in-place on out
// ---------------------------------------------------------------------------
__global__ __launch_bounds__(256) void ln_kernel(float* __restrict__ out,
        const float* __restrict__ g, const float* __restrict__ b) {
    __shared__ float wr_[4], wr2[4];
    const int t = blockIdx.x, tid = threadIdx.x;
    const float4 v = *(const float4*)&out[(size_t)t * D + tid * 4];
    float s = v.x + v.y + v.z + v.w;
    float s2 = v.x * v.x + v.y * v.y + v.z * v.z + v.w * v.w;
    for (int off = 32; off; off >>= 1) { s += __shfl_xor(s, off); s2 += __shfl_xor(s2, off); }
    if ((tid & 63) == 0) { wr_[tid >> 6] = s; wr2[tid >> 6] = s2; }
    __syncthreads();
    const float sum = wr_[0] + wr_[1] + wr_[2] + wr_[3];
    const float sum2 = wr2[0] + wr2[1] + wr2[2] + wr2[3];
    const float mu = sum * (1.f / D);
    const float var = sum2 * (1.f / D) - mu * mu;
    const float inv = rsqrtf(var + 1e-5f);
    const float4 g4 = *(const float4*)&g[tid * 4];
    const float4 b4 = *(const float4*)&b[tid * 4];
    float4 o;
    o.x = (v.x - mu) * inv * g4.x + b4.x;
    o.y = (v.y - mu) * inv * g4.y + b4.y;
    o.z = (v.z - mu) * inv * g4.z + b4.z;
    o.w = (v.w - mu) * inv * g4.w + b4.w;
    *(float4*)&out[(size_t)t * D + tid * 4] = o;
}

// ---------------------------------------------------------------------------
extern "C" void kernel_launch(void* const* d_in, const int* in_sizes, int n_in,
                              void* d_out, int out_size, void* d_ws, size_t ws_size,
                              hipStream_t stream) {
    const float* x       = (const float*)d_in[0];
    const float* col_emb = (const float*)d_in[1];
    const float* gate_w1 = (const float*)d_in[2];
    const float* gate_b1 = (const float*)d_in[3];
    const float* gate_w2 = (const float*)d_in[4];
    const float* gate_b2 = (const float*)d_in[5];
    const float* W_cols  = (const float*)d_in[6];
    const float* b_cols  = (const float*)d_in[7];
    const float* proj_w  = (const float*)d_in[8];
    const float* proj_b  = (const float*)d_in[9];
    const float* ln_g    = (const float*)d_in[10];
    const float* ln_b    = (const float*)d_in[11];
    float* out = (float*)d_out;

    char* w = (char*)d_ws;
    short* xb    = (short*)w;  w += (size_t)TOK * D * 2;           // 16 MB
    short* Hb    = (short*)w;  w += (size_t)TOK * DH * 2;          //  8 MB
    short* actb  = (short*)w;  w += (size_t)TOK * N * 2 + 65536;   //  4 MB + slack
    short* w1T   = (short*)w;  w += (size_t)DH * D * 2;            //  1 MB
    short* WcT   = (short*)w;  w += (size_t)C * N * D * 2;         //  8 MB
    short* pwT   = (short*)w;  w += (size_t)C * D * N * 2;         //  8 MB
    float* wgt   = (float*)w;  w += TOK * 4;
    float* cnorm = (float*)w;  w += 64;
    int*   idx   = (int*)w;    w += TOK * 4;
    int*   order = (int*)w;    w += TOK * 4;
    int*   counts= (int*)w;    w += 64;
    int*   offs  = (int*)w;    w += 64;
    int*   cursor= (int*)w;    w += 64;

    hipLaunchKernelGGL(prep_kernel, dim3(1), dim3(256), 0, stream, col_emb, cnorm);
    hipLaunchKernelGGL(conv_kernel, dim3(2048), dim3(256), 0, stream,
                       x, xb, TOK * D / 4);
    hipLaunchKernelGGL(tconv_kernel, dim3(DH / 64, D / 64, 1), dim3(256), 0, stream,
                       gate_w1, w1T, D, DH);
    hipLaunchKernelGGL(tconv_kernel, dim3(N / 64, D / 64, C), dim3(256), 0, stream,
                       W_cols, WcT, D, N);
    hipLaunchKernelGGL(tconv_kernel, dim3(D / 64, N / 64, C), dim3(256), 0, stream,
                       proj_w, pwT, N, D);
    // gate GEMM (bf16 MFMA) -> Hb
    hipLaunchKernelGGL((mfma_tile<0>), dim3(TOK / 64, DH / 64, 1), dim3(256), 0, stream,
                       xb, w1T, gate_b1, nullptr, nullptr, nullptr, nullptr, nullptr,
                       Hb, nullptr);
    hipLaunchKernelGGL(route_kernel, dim3(TOK / RT_T), dim3(256), 0, stream,
                       x, Hb, col_emb, cnorm, gate_w2, gate_b2, idx, wgt);
    hipLaunchKernelGGL(hist_kernel, dim3(1), dim3(256), 0, stream,
                       idx, counts, offs, cursor);
    hipLaunchKernelGGL(scatter_kernel, dim3(TOK / 256), dim3(256), 0, stream,
                       idx, cursor, order);
    // column GEMM1 (grouped, bf16 MFMA) -> actb
    hipLaunchKernelGGL((mfma_tile<1>), dim3(TOK / 64, N / 64, C), dim3(256), 0, stream,
                       xb, WcT, b_cols, nullptr, counts, offs, order, wgt,
                       actb, nullptr);
    // column GEMM2 (grouped, bf16 MFMA) -> out (+bias+residual)
    hipLaunchKernelGGL((mfma_tile<2>), dim3(TOK / 64, D / 64, C), dim3(256), 0, stream,
                       actb, pwT, proj_b, x, counts, offs, order, wgt,
                       nullptr, out);
    hipLaunchKernelGGL(ln_kernel, dim3(TOK), dim3(256), 0, stream, out, ln_g, ln_b);
}